// Round 19
// baseline (217.001 us; speedup 1.0000x reference)
//
#include <hip/hip_runtime.h>

// LayerGCN: out = relu(bn2(relu(bn1( (D^-.5 (A>=.1) D^-.5) V @ W1 )) @ W2))
// B=4096, N=128, C_IN=64, C_HID=256, C_OUT=128.
// R19 = R18 fused kernel + software-pipelined next-batch loads (T14):
// V loads issued after bar2 (held 32 regs); A loads streamed 2/T-iter through a
// 16-reg window, compressed to threshold BITS (2 regs) as they arrive; afrag
// rebuilt from bits at next GEMM1. Same math as R18, different placement.

#define THRESH 0.1f
#define BN_EPS 1e-5f

typedef __attribute__((ext_vector_type(8))) short bf16x8;
typedef __attribute__((ext_vector_type(4))) float f32x4;

__device__ __forceinline__ unsigned short f2bf(float f) {
    union { float f; unsigned u; } x; x.f = f;
    unsigned r = x.u + 0x7FFFu + ((x.u >> 16) & 1u);   // RNE
    return (unsigned short)(r >> 16);
}

__device__ __forceinline__ unsigned cvt_pk(float lo, float hi) {
    unsigned r;
    asm("v_cvt_pk_bf16_f32 %0, %1, %2" : "=v"(r) : "v"(lo), "v"(hi));
    return r;
}

__device__ __forceinline__ unsigned thbyte(f32x4 x0, f32x4 x1) {
    return  (unsigned)(x0.x >= THRESH)
         | ((unsigned)(x0.y >= THRESH) << 1)
         | ((unsigned)(x0.z >= THRESH) << 2)
         | ((unsigned)(x0.w >= THRESH) << 3)
         | ((unsigned)(x1.x >= THRESH) << 4)
         | ((unsigned)(x1.y >= THRESH) << 5)
         | ((unsigned)(x1.z >= THRESH) << 6)
         | ((unsigned)(x1.w >= THRESH) << 7);
}

// rebuild one bf16x8 a_th fragment from an 8-bit mask (1.0f bf16 = 0x3F80)
__device__ __forceinline__ bf16x8 bits2frag(unsigned byte) {
    union { unsigned u[4]; bf16x8 v; } f;
#pragma unroll
    for (int q = 0; q < 4; ++q)
        f.u[q] = (((byte >> (2 * q)) & 1u) * 0x3F80u)
               | (((byte >> (2 * q + 1)) & 1u) * 0x3F800000u);
    return f.v;
}

// ---------------- prep (unchanged from R14/R18) ----------------
__global__ void gcn_prep(const float* __restrict__ W1, const float* __restrict__ b1,
                         const float* __restrict__ g1, const float* __restrict__ be1,
                         const float* __restrict__ rm1, const float* __restrict__ rv1,
                         const float* __restrict__ W2, const float* __restrict__ b2,
                         const float* __restrict__ g2, const float* __restrict__ be2,
                         const float* __restrict__ rm2, const float* __restrict__ rv2,
                         unsigned short* __restrict__ W1s, unsigned short* __restrict__ W2s,
                         float* __restrict__ sh1, float* __restrict__ sh2) {
    int t = blockIdx.x * blockDim.x + threadIdx.x;       // 0..32767
    if (t < 256 * 64) {                                  // W1s: n = t/64, kp = t%64
        int n = t >> 6, kp = t & 63;
        int sp = kp >> 3, lo = kp & 7;
        int s  = sp ^ (n & 7);
        int k2 = s * 8 + lo;
        int r = k2 & 3, aa = (k2 >> 2) & 1, gg = (k2 >> 3) & 3, T = k2 >> 5;
        int k = T * 32 + aa * 16 + gg * 4 + r;
        float sc = g1[n] * rsqrtf(rv1[n] + BN_EPS);
        W1s[t] = f2bf(W1[k * 256 + n] * sc);
    }
    {                                                    // W2s: n = t/256, kp = t%256
        int n = t >> 8, kp = t & 255;
        int sp = kp >> 3, lo = kp & 7;
        int s  = sp ^ (n & 7);
        int k2 = s * 8 + lo;
        int r = k2 & 3, aa = (k2 >> 2) & 1, gg = (k2 >> 3) & 3, T = k2 >> 5;
        int k = T * 32 + aa * 16 + gg * 4 + r;
        float sc = g2[n] * rsqrtf(rv2[n] + BN_EPS);
        W2s[t] = f2bf(W2[k * 128 + n] * sc);
    }
    if (t < 256) {
        float s = g1[t] * rsqrtf(rv1[t] + BN_EPS);
        sh1[t] = (b1[t] - rm1[t]) * s + be1[t];
    }
    if (t < 128) {
        float s = g2[t] * rsqrtf(rv2[t] + BN_EPS);
        sh2[t] = (b2[t] - rm2[t]) * s + be2[t];
    }
}

// ---------------- fused kernel: A,V -> out ----------------
// LDS: W1L @0 (32768) | W2L @32768 (65536) | vtt[2] @98304 (34816)
//      sh1 @133120 (1024) | sh2 @134144 (512) -> 134656 B
__global__ void __launch_bounds__(512, 1)
gcn_fused(const float* __restrict__ A, const float* __restrict__ V,
          const unsigned short* __restrict__ W1s, const unsigned short* __restrict__ W2s,
          const float* __restrict__ sh1g, const float* __restrict__ sh2g,
          float* __restrict__ out) {
    __shared__ char smem[134656];
    unsigned short* W1L = (unsigned short*)smem;            // [256][64] swizzled
    unsigned short* W2L = (unsigned short*)(smem + 32768);  // [128][256] swizzled
    float* s_sh1 = (float*)(smem + 133120);
    float* s_sh2 = (float*)(smem + 134144);

    const int t    = threadIdx.x;
    const int lane = t & 63;
    const int w    = t >> 6;         // 0..7
    const int r16  = lane & 15;
    const int g    = lane >> 4;
    const int bs   = w >> 2;         // batch slot (0/1)
    const int wl   = w & 3;          // wave-local row group

    unsigned short* vt = (unsigned short*)(smem + 98304) + bs * (64 * 136);

    // ---- stage weights once ----
#pragma unroll
    for (int q = 0; q < 4; ++q)
        *(f32x4*)(smem + t * 64 + q * 16) = *(const f32x4*)((const char*)W1s + t * 64 + q * 16);
#pragma unroll
    for (int q = 0; q < 8; ++q)
        *(f32x4*)(smem + 32768 + t * 128 + q * 16) =
            *(const f32x4*)((const char*)W2s + t * 128 + q * 16);
    if (t < 256) s_sh1[t] = sh1g[t];
    if (t < 128) s_sh2[t] = sh2g[t];

    const size_t b00 = (size_t)blockIdx.x * 16;

    const int mloc  = lane & 31;
    const int chalf = (lane >> 5) * 32;
    const size_t voff = (size_t)(32 * wl + mloc) * 64 + chalf;
    const size_t aoff = (size_t)(32 * wl + r16) * 128;

    // ---- prologue: batch(bs) -> bits, dinv, vtt ----
    unsigned bc0 = 0, bc1 = 0;       // current-batch threshold bits [mt]
    float dinv0, dinv1;
    {
        const size_t b = b00 + bs;
        const float* vb = V + b * 8192 + voff;
        f32x4 pv[8];
#pragma unroll
        for (int q = 0; q < 8; ++q) pv[q] = *(const f32x4*)(vb + 4 * q);

        const float* ab = A + b * 16384 + aoff;
#pragma unroll
        for (int p = 0; p < 8; ++p) {
            const int mt = p >> 2, ks = p & 3;
            const float* pp = ab + mt * 2048 + ks * 32 + 8 * g;
            f32x4 x0 = *(const f32x4*)pp;
            f32x4 x1 = *(const f32x4*)(pp + 4);
            unsigned byte = thbyte(x0, x1);
            if (mt == 0) bc0 |= byte << (ks * 8); else bc1 |= byte << (ks * 8);
        }
        int cnt0 = __popc(bc0), cnt1 = __popc(bc1);
        cnt0 += __shfl_xor(cnt0, 16); cnt0 += __shfl_xor(cnt0, 32);
        cnt1 += __shfl_xor(cnt1, 16); cnt1 += __shfl_xor(cnt1, 32);
        dinv0 = rsqrtf((float)cnt0);
        dinv1 = rsqrtf((float)cnt1);

        float dm = (lane & 16) ? dinv1 : dinv0;
        int m = 32 * wl + mloc;
#pragma unroll
        for (int q = 0; q < 8; ++q) {
            int c = chalf + 4 * q;
            vt[(c + 0) * 136 + m] = f2bf(pv[q].x * dm);
            vt[(c + 1) * 136 + m] = f2bf(pv[q].y * dm);
            vt[(c + 2) * 136 + m] = f2bf(pv[q].z * dm);
            vt[(c + 3) * 136 + m] = f2bf(pv[q].w * dm);
        }
    }
    __syncthreads();   // bar1: weights + vtt(0) ready

#pragma unroll 1
    for (int it = 0; it < 8; ++it) {
        const size_t b  = b00 + it * 2 + bs;
        const size_t bn = (b00 + (it + 1) * 2 + bs < 4096) ? (b00 + (it + 1) * 2 + bs) : 4095;

        // ---- rebuild afrag from bits (VALU only) ----
        bf16x8 afrag[2][4];
#pragma unroll
        for (int ks = 0; ks < 4; ++ks) {
            afrag[0][ks] = bits2frag((bc0 >> (ks * 8)) & 0xFFu);
            afrag[1][ks] = bits2frag((bc1 >> (ks * 8)) & 0xFFu);
        }

        // ---- GEMM1 (transposed): h^T = v̂^T @ a_th^T ----
        f32x4 acc1[4][2];
#pragma unroll
        for (int ct = 0; ct < 4; ++ct)
#pragma unroll
            for (int mt = 0; mt < 2; ++mt) acc1[ct][mt] = f32x4{0.f, 0.f, 0.f, 0.f};
#pragma unroll
        for (int ks = 0; ks < 4; ++ks)
#pragma unroll
            for (int ct = 0; ct < 4; ++ct) {
                bf16x8 av = *(const bf16x8*)(vt + (ct * 16 + r16) * 136 + ks * 32 + 8 * g);
                acc1[ct][0] = __builtin_amdgcn_mfma_f32_16x16x32_bf16(av, afrag[0][ks], acc1[ct][0], 0, 0, 0);
                acc1[ct][1] = __builtin_amdgcn_mfma_f32_16x16x32_bf16(av, afrag[1][ks], acc1[ct][1], 0, 0, 0);
            }
        bf16x8 bh[2][2];
#pragma unroll
        for (int mt = 0; mt < 2; ++mt) {
            float d = (mt == 0) ? dinv0 : dinv1;
#pragma unroll
            for (int ks2 = 0; ks2 < 2; ++ks2) {
                union { unsigned u[4]; bf16x8 v; } pk;
                pk.u[0] = cvt_pk(acc1[2 * ks2][mt][0] * d,     acc1[2 * ks2][mt][1] * d);
                pk.u[1] = cvt_pk(acc1[2 * ks2][mt][2] * d,     acc1[2 * ks2][mt][3] * d);
                pk.u[2] = cvt_pk(acc1[2 * ks2 + 1][mt][0] * d, acc1[2 * ks2 + 1][mt][1] * d);
                pk.u[3] = cvt_pk(acc1[2 * ks2 + 1][mt][2] * d, acc1[2 * ks2 + 1][mt][3] * d);
                bh[mt][ks2] = pk.v;
            }
        }
        __syncthreads();   // bar2: vtt consumed -> safe to overwrite later

        // ---- issue next-batch V loads (held through T-loop) + first A pairs ----
        const float* vbn = V + bn * 8192 + voff;
        f32x4 pv[8];
#pragma unroll
        for (int q = 0; q < 8; ++q) pv[q] = *(const f32x4*)(vbn + 4 * q);

        const float* abn = A + bn * 16384 + aoff;
        f32x4 paA[2], paB[2];                      // rolling 2-pair window
        paA[0] = *(const f32x4*)(abn + 0 * 2048 + 0 * 32 + 8 * g);   // pair 0 (mt0,ks0)
        paB[0] = *(const f32x4*)(abn + 0 * 2048 + 0 * 32 + 8 * g + 4);
        paA[1] = *(const f32x4*)(abn + 0 * 2048 + 1 * 32 + 8 * g);   // pair 1 (mt0,ks1)
        paB[1] = *(const f32x4*)(abn + 0 * 2048 + 1 * 32 + 8 * g + 4);

        unsigned bn0 = 0, bn1 = 0;     // next-batch bits

        f32x4 acc3[2][8];
#pragma unroll
        for (int mt = 0; mt < 2; ++mt)
#pragma unroll
            for (int ct = 0; ct < 8; ++ct) acc3[mt][ct] = f32x4{0.f, 0.f, 0.f, 0.f};

#pragma unroll
        for (int T = 0; T < 8; ++T) {
            // ---- T-body: GEMM2 + BN1/ReLU + GEMM3 ----
            f32x4 a2[2][2];
#pragma unroll
            for (int mt = 0; mt < 2; ++mt)
#pragma unroll
                for (int ctp = 0; ctp < 2; ++ctp) a2[mt][ctp] = f32x4{0.f, 0.f, 0.f, 0.f};
#pragma unroll
            for (int ctp = 0; ctp < 2; ++ctp) {
                int n = (2 * T + ctp) * 16 + r16;
#pragma unroll
                for (int ks2 = 0; ks2 < 2; ++ks2) {
                    int sp = (ks2 * 4 + g) ^ (n & 7);
                    bf16x8 aw = *(const bf16x8*)(W1L + n * 64 + sp * 8);
                    a2[0][ctp] = __builtin_amdgcn_mfma_f32_16x16x32_bf16(aw, bh[0][ks2], a2[0][ctp], 0, 0, 0);
                    a2[1][ctp] = __builtin_amdgcn_mfma_f32_16x16x32_bf16(aw, bh[1][ks2], a2[1][ctp], 0, 0, 0);
                }
            }
            union { unsigned u[4]; bf16x8 v; } af[2];
#pragma unroll
            for (int ctp = 0; ctp < 2; ++ctp) {
                f32x4 sh = *(const f32x4*)(s_sh1 + (2 * T + ctp) * 16 + 4 * g);
#pragma unroll
                for (int mt = 0; mt < 2; ++mt) {
                    float y0 = fmaxf(a2[mt][ctp][0] + sh.x, 0.f);
                    float y1 = fmaxf(a2[mt][ctp][1] + sh.y, 0.f);
                    float y2 = fmaxf(a2[mt][ctp][2] + sh.z, 0.f);
                    float y3 = fmaxf(a2[mt][ctp][3] + sh.w, 0.f);
                    af[mt].u[2 * ctp + 0] = cvt_pk(y0, y1);
                    af[mt].u[2 * ctp + 1] = cvt_pk(y2, y3);
                }
            }
#pragma unroll
            for (int ct3 = 0; ct3 < 8; ++ct3) {
                int n  = ct3 * 16 + r16;
                int sp = (T * 4 + g) ^ (n & 7);
                bf16x8 bw = *(const bf16x8*)(W2L + n * 256 + sp * 8);
                acc3[0][ct3] = __builtin_amdgcn_mfma_f32_16x16x32_bf16(af[0].v, bw, acc3[0][ct3], 0, 0, 0);
                acc3[1][ct3] = __builtin_amdgcn_mfma_f32_16x16x32_bf16(af[1].v, bw, acc3[1][ct3], 0, 0, 0);
            }

            // ---- pipeline: threshold pair T, issue pair T+2 (static indices) ----
            {
                const int mt = T >> 2, ks = T & 3;
                unsigned byte = thbyte(paA[T & 1], paB[T & 1]);
                if (mt == 0) bn0 |= byte << (ks * 8); else bn1 |= byte << (ks * 8);
                if (T + 2 < 8) {
                    const int p2 = T + 2;
                    const int mt2 = p2 >> 2, ks2p = p2 & 3;
                    paA[T & 1] = *(const f32x4*)(abn + mt2 * 2048 + ks2p * 32 + 8 * g);
                    paB[T & 1] = *(const f32x4*)(abn + mt2 * 2048 + ks2p * 32 + 8 * g + 4);
                }
            }
        }

        // ---- BN2 shift + ReLU -> global ----
        float* ob = out + (b * 128 + (size_t)(32 * wl)) * 128;
#pragma unroll
        for (int ct3 = 0; ct3 < 8; ++ct3) {
            int c = ct3 * 16 + r16;
            float sh = s_sh2[c];
#pragma unroll
            for (int mt = 0; mt < 2; ++mt)
#pragma unroll
                for (int r = 0; r < 4; ++r) {
                    int row = 16 * mt + 4 * g + r;
                    ob[row * 128 + c] = fmaxf(acc3[mt][ct3][r] + sh, 0.f);
                }
        }

        // ---- finish next batch: counts -> dinv, write vtt from pv ----
        {
            int cnt0 = __popc(bn0), cnt1 = __popc(bn1);
            cnt0 += __shfl_xor(cnt0, 16); cnt0 += __shfl_xor(cnt0, 32);
            cnt1 += __shfl_xor(cnt1, 16); cnt1 += __shfl_xor(cnt1, 32);
            dinv0 = rsqrtf((float)cnt0);
            dinv1 = rsqrtf((float)cnt1);
            bc0 = bn0; bc1 = bn1;

            float dm = (lane & 16) ? dinv1 : dinv0;
            int m = 32 * wl + mloc;
#pragma unroll
            for (int q = 0; q < 8; ++q) {
                int c = chalf + 4 * q;
                vt[(c + 0) * 136 + m] = f2bf(pv[q].x * dm);
                vt[(c + 1) * 136 + m] = f2bf(pv[q].y * dm);
                vt[(c + 2) * 136 + m] = f2bf(pv[q].z * dm);
                vt[(c + 3) * 136 + m] = f2bf(pv[q].w * dm);
            }
        }
        if (it < 7) __syncthreads();   // bar1: vtt(it+1) ready
    }
}

extern "C" void kernel_launch(void* const* d_in, const int* in_sizes, int n_in,
                              void* d_out, int out_size, void* d_ws, size_t ws_size,
                              hipStream_t stream) {
    (void)in_sizes; (void)n_in; (void)out_size; (void)ws_size;
    const float* a   = (const float*)d_in[0];
    const float* v   = (const float*)d_in[1];
    const float* W1  = (const float*)d_in[2];
    const float* b1  = (const float*)d_in[3];
    const float* g1  = (const float*)d_in[4];
    const float* be1 = (const float*)d_in[5];
    const float* rm1 = (const float*)d_in[6];
    const float* rv1 = (const float*)d_in[7];
    const float* W2  = (const float*)d_in[8];
    const float* b2  = (const float*)d_in[9];
    const float* g2  = (const float*)d_in[10];
    const float* be2 = (const float*)d_in[11];
    const float* rm2 = (const float*)d_in[12];
    const float* rv2 = (const float*)d_in[13];

    char* ws = (char*)d_ws;
    unsigned short* W1s = (unsigned short*)ws;             // 32768 B
    unsigned short* W2s = (unsigned short*)(ws + 32768);   // 65536 B
    float* sh1 = (float*)(ws + 98304);                     // 1024 B
    float* sh2 = (float*)(ws + 99328);                     // 512 B

    gcn_prep<<<128, 256, 0, stream>>>(W1, b1, g1, be1, rm1, rv1,
                                      W2, b2, g2, be2, rm2, rv2,
                                      W1s, W2s, sh1, sh2);
    gcn_fused<<<256, 512, 0, stream>>>(a, v, W1s, W2s, sh1, sh2, (float*)d_out);
}

// Round 20
// 189.146 us; speedup vs baseline: 1.1473x; 1.1473x over previous
//
#include <hip/hip_runtime.h>

// LayerGCN: out = relu(bn2(relu(bn1( (D^-.5 (A>=.1) D^-.5) V @ W1 )) @ W2))
// B=4096, N=128, C_IN=64, C_HID=256, C_OUT=128.
// R20 = R18 verbatim (pre-committed revert from R19's spill regression).
// FUSED prop+mlp: 512-thr blocks (8 waves), waves 0-3 -> batch0, 4-7 -> batch1;
// 16 batches/block, grid 256 (1 block/CU). W1+W2 staged once in LDS (96KB) +
// vtt[2] (34.8KB). h stays in registers. 2 barriers/batch. Live <= 128 clean.

#define THRESH 0.1f
#define BN_EPS 1e-5f

typedef __attribute__((ext_vector_type(8))) short bf16x8;
typedef __attribute__((ext_vector_type(4))) float f32x4;

__device__ __forceinline__ unsigned short f2bf(float f) {
    union { float f; unsigned u; } x; x.f = f;
    unsigned r = x.u + 0x7FFFu + ((x.u >> 16) & 1u);   // RNE
    return (unsigned short)(r >> 16);
}

__device__ __forceinline__ unsigned cvt_pk(float lo, float hi) {
    unsigned r;
    asm("v_cvt_pk_bf16_f32 %0, %1, %2" : "=v"(r) : "v"(lo), "v"(hi));
    return r;
}

// ---------------- prep ----------------
// k-bijection within each 32-chunk (k summed -> legal): register slot j of
// lane-group g holds logical k = 32T + 16(j>>2) + 4g + (j&3).
// LDS bank-swizzle baked in: 16B-slot s stored at sp = s ^ (n&7).
__global__ void gcn_prep(const float* __restrict__ W1, const float* __restrict__ b1,
                         const float* __restrict__ g1, const float* __restrict__ be1,
                         const float* __restrict__ rm1, const float* __restrict__ rv1,
                         const float* __restrict__ W2, const float* __restrict__ b2,
                         const float* __restrict__ g2, const float* __restrict__ be2,
                         const float* __restrict__ rm2, const float* __restrict__ rv2,
                         unsigned short* __restrict__ W1s, unsigned short* __restrict__ W2s,
                         float* __restrict__ sh1, float* __restrict__ sh2) {
    int t = blockIdx.x * blockDim.x + threadIdx.x;       // 0..32767
    if (t < 256 * 64) {                                  // W1s: n = t/64, kp = t%64
        int n = t >> 6, kp = t & 63;
        int sp = kp >> 3, lo = kp & 7;
        int s  = sp ^ (n & 7);
        int k2 = s * 8 + lo;
        int r = k2 & 3, aa = (k2 >> 2) & 1, gg = (k2 >> 3) & 3, T = k2 >> 5;
        int k = T * 32 + aa * 16 + gg * 4 + r;
        float sc = g1[n] * rsqrtf(rv1[n] + BN_EPS);
        W1s[t] = f2bf(W1[k * 256 + n] * sc);
    }
    {                                                    // W2s: n = t/256, kp = t%256
        int n = t >> 8, kp = t & 255;
        int sp = kp >> 3, lo = kp & 7;
        int s  = sp ^ (n & 7);
        int k2 = s * 8 + lo;
        int r = k2 & 3, aa = (k2 >> 2) & 1, gg = (k2 >> 3) & 3, T = k2 >> 5;
        int k = T * 32 + aa * 16 + gg * 4 + r;
        float sc = g2[n] * rsqrtf(rv2[n] + BN_EPS);
        W2s[t] = f2bf(W2[k * 128 + n] * sc);
    }
    if (t < 256) {
        float s = g1[t] * rsqrtf(rv1[t] + BN_EPS);
        sh1[t] = (b1[t] - rm1[t]) * s + be1[t];
    }
    if (t < 128) {
        float s = g2[t] * rsqrtf(rv2[t] + BN_EPS);
        sh2[t] = (b2[t] - rm2[t]) * s + be2[t];
    }
}

// ---------------- fused kernel: A,V -> out ----------------
// LDS map: W1L @0 (32768) | W2L @32768 (65536) | vtt[2] @98304 (34816)
//          sh1 @133120 (1024) | sh2 @134144 (512)  -> total 134656 B
__global__ void __launch_bounds__(512, 1)
gcn_fused(const float* __restrict__ A, const float* __restrict__ V,
          const unsigned short* __restrict__ W1s, const unsigned short* __restrict__ W2s,
          const float* __restrict__ sh1g, const float* __restrict__ sh2g,
          float* __restrict__ out) {
    __shared__ char smem[134656];
    unsigned short* W1L = (unsigned short*)smem;            // [256][64] swizzled
    unsigned short* W2L = (unsigned short*)(smem + 32768);  // [128][256] swizzled
    float* s_sh1 = (float*)(smem + 133120);
    float* s_sh2 = (float*)(smem + 134144);

    const int t    = threadIdx.x;
    const int lane = t & 63;
    const int w    = t >> 6;         // 0..7
    const int r16  = lane & 15;
    const int g    = lane >> 4;
    const int bs   = w >> 2;         // batch slot within superbatch (0/1)
    const int wl   = w & 3;          // wave-local row group (32 rows)

    unsigned short* vt = (unsigned short*)(smem + 98304) + bs * (64 * 136);

    // ---- stage weights once ----
#pragma unroll
    for (int q = 0; q < 4; ++q)
        *(f32x4*)(smem + t * 64 + q * 16) = *(const f32x4*)((const char*)W1s + t * 64 + q * 16);
#pragma unroll
    for (int q = 0; q < 8; ++q)
        *(f32x4*)(smem + 32768 + t * 128 + q * 16) =
            *(const f32x4*)((const char*)W2s + t * 128 + q * 16);
    if (t < 256) s_sh1[t] = sh1g[t];
    if (t < 128) s_sh2[t] = sh2g[t];

    const size_t b00 = (size_t)blockIdx.x * 16;   // 8 superbatches x 2 batches

    const int mloc  = lane & 31;
    const int chalf = (lane >> 5) * 32;

    // ---- prologue: load/threshold superbatch 0, write vtt ----
    bf16x8 afrag[2][4];
    float dinv0, dinv1;
    {
        const size_t b = b00 + bs;
        const float* vb = V + b * 8192 + (size_t)(32 * wl + mloc) * 64 + chalf;
        f32x4 pv[8];
#pragma unroll
        for (int q = 0; q < 8; ++q) pv[q] = *(const f32x4*)(vb + 4 * q);

        const float* ab = A + b * 16384 + (size_t)(32 * wl + r16) * 128;
        int cnt0 = 0, cnt1 = 0;
#pragma unroll
        for (int mt = 0; mt < 2; ++mt)
#pragma unroll
            for (int ks = 0; ks < 4; ++ks) {
                const float* p = ab + mt * 2048 + ks * 32 + 8 * g;
                f32x4 x0 = *(const f32x4*)p;
                f32x4 x1 = *(const f32x4*)(p + 4);
                union { unsigned short s[8]; bf16x8 v; } u;
                u.s[0] = (x0.x >= THRESH) ? (unsigned short)0x3F80u : (unsigned short)0u;
                u.s[1] = (x0.y >= THRESH) ? (unsigned short)0x3F80u : (unsigned short)0u;
                u.s[2] = (x0.z >= THRESH) ? (unsigned short)0x3F80u : (unsigned short)0u;
                u.s[3] = (x0.w >= THRESH) ? (unsigned short)0x3F80u : (unsigned short)0u;
                u.s[4] = (x1.x >= THRESH) ? (unsigned short)0x3F80u : (unsigned short)0u;
                u.s[5] = (x1.y >= THRESH) ? (unsigned short)0x3F80u : (unsigned short)0u;
                u.s[6] = (x1.z >= THRESH) ? (unsigned short)0x3F80u : (unsigned short)0u;
                u.s[7] = (x1.w >= THRESH) ? (unsigned short)0x3F80u : (unsigned short)0u;
                afrag[mt][ks] = u.v;
                int c = (x0.x >= THRESH) + (x0.y >= THRESH) + (x0.z >= THRESH) + (x0.w >= THRESH)
                      + (x1.x >= THRESH) + (x1.y >= THRESH) + (x1.z >= THRESH) + (x1.w >= THRESH);
                if (mt == 0) cnt0 += c; else cnt1 += c;
            }
        cnt0 += __shfl_xor(cnt0, 16); cnt0 += __shfl_xor(cnt0, 32);
        cnt1 += __shfl_xor(cnt1, 16); cnt1 += __shfl_xor(cnt1, 32);
        dinv0 = rsqrtf((float)cnt0);
        dinv1 = rsqrtf((float)cnt1);

        float dm = (lane & 16) ? dinv1 : dinv0;
        int m = 32 * wl + mloc;
#pragma unroll
        for (int q = 0; q < 8; ++q) {
            int c = chalf + 4 * q;
            vt[(c + 0) * 136 + m] = f2bf(pv[q].x * dm);
            vt[(c + 1) * 136 + m] = f2bf(pv[q].y * dm);
            vt[(c + 2) * 136 + m] = f2bf(pv[q].z * dm);
            vt[(c + 3) * 136 + m] = f2bf(pv[q].w * dm);
        }
    }
    __syncthreads();   // bar1: weights + vtt(superbatch 0) ready

#pragma unroll 1
    for (int it = 0; it < 8; ++it) {
        const size_t b  = b00 + it * 2 + bs;
        const size_t mb = (size_t)(32 * wl);   // wave's rows within batch

        // ---- GEMM1 (transposed): h^T = v̂^T @ a_th^T; m lane-local ----
        f32x4 acc1[4][2];
#pragma unroll
        for (int ct = 0; ct < 4; ++ct)
#pragma unroll
            for (int mt = 0; mt < 2; ++mt) acc1[ct][mt] = f32x4{0.f, 0.f, 0.f, 0.f};
#pragma unroll
        for (int ks = 0; ks < 4; ++ks)
#pragma unroll
            for (int ct = 0; ct < 4; ++ct) {
                bf16x8 av = *(const bf16x8*)(vt + (ct * 16 + r16) * 136 + ks * 32 + 8 * g);
                acc1[ct][0] = __builtin_amdgcn_mfma_f32_16x16x32_bf16(av, afrag[0][ks], acc1[ct][0], 0, 0, 0);
                acc1[ct][1] = __builtin_amdgcn_mfma_f32_16x16x32_bf16(av, afrag[1][ks], acc1[ct][1], 0, 0, 0);
            }
        // h = dinv[m]*h_pre -> bijection-packed bh
        bf16x8 bh[2][2];
#pragma unroll
        for (int mt = 0; mt < 2; ++mt) {
            float d = (mt == 0) ? dinv0 : dinv1;
#pragma unroll
            for (int ks2 = 0; ks2 < 2; ++ks2) {
                union { unsigned u[4]; bf16x8 v; } pk;
                pk.u[0] = cvt_pk(acc1[2 * ks2][mt][0] * d,     acc1[2 * ks2][mt][1] * d);
                pk.u[1] = cvt_pk(acc1[2 * ks2][mt][2] * d,     acc1[2 * ks2][mt][3] * d);
                pk.u[2] = cvt_pk(acc1[2 * ks2 + 1][mt][0] * d, acc1[2 * ks2 + 1][mt][1] * d);
                pk.u[3] = cvt_pk(acc1[2 * ks2 + 1][mt][2] * d, acc1[2 * ks2 + 1][mt][3] * d);
                bh[mt][ks2] = pk.v;
            }
        }
        __syncthreads();   // bar2: all GEMM1 vtt reads done -> vtt reusable

        // ---- T-loop: GEMM2 + BN1/ReLU + GEMM3 ----
        f32x4 acc3[2][8];
#pragma unroll
        for (int mt = 0; mt < 2; ++mt)
#pragma unroll
            for (int ct = 0; ct < 8; ++ct) acc3[mt][ct] = f32x4{0.f, 0.f, 0.f, 0.f};

#pragma unroll
        for (int T = 0; T < 8; ++T) {
            f32x4 a2[2][2];
#pragma unroll
            for (int mt = 0; mt < 2; ++mt)
#pragma unroll
                for (int ctp = 0; ctp < 2; ++ctp) a2[mt][ctp] = f32x4{0.f, 0.f, 0.f, 0.f};
#pragma unroll
            for (int ctp = 0; ctp < 2; ++ctp) {
                int n = (2 * T + ctp) * 16 + r16;
#pragma unroll
                for (int ks2 = 0; ks2 < 2; ++ks2) {
                    int sp = (ks2 * 4 + g) ^ (n & 7);
                    bf16x8 aw = *(const bf16x8*)(W1L + n * 64 + sp * 8);
                    a2[0][ctp] = __builtin_amdgcn_mfma_f32_16x16x32_bf16(aw, bh[0][ks2], a2[0][ctp], 0, 0, 0);
                    a2[1][ctp] = __builtin_amdgcn_mfma_f32_16x16x32_bf16(aw, bh[1][ks2], a2[1][ctp], 0, 0, 0);
                }
            }
            union { unsigned u[4]; bf16x8 v; } af[2];
#pragma unroll
            for (int ctp = 0; ctp < 2; ++ctp) {
                f32x4 sh = *(const f32x4*)(s_sh1 + (2 * T + ctp) * 16 + 4 * g);
#pragma unroll
                for (int mt = 0; mt < 2; ++mt) {
                    float y0 = fmaxf(a2[mt][ctp][0] + sh.x, 0.f);
                    float y1 = fmaxf(a2[mt][ctp][1] + sh.y, 0.f);
                    float y2 = fmaxf(a2[mt][ctp][2] + sh.z, 0.f);
                    float y3 = fmaxf(a2[mt][ctp][3] + sh.w, 0.f);
                    af[mt].u[2 * ctp + 0] = cvt_pk(y0, y1);
                    af[mt].u[2 * ctp + 1] = cvt_pk(y2, y3);
                }
            }
#pragma unroll
            for (int ct3 = 0; ct3 < 8; ++ct3) {
                int n  = ct3 * 16 + r16;
                int sp = (T * 4 + g) ^ (n & 7);
                bf16x8 bw = *(const bf16x8*)(W2L + n * 256 + sp * 8);
                acc3[0][ct3] = __builtin_amdgcn_mfma_f32_16x16x32_bf16(af[0].v, bw, acc3[0][ct3], 0, 0, 0);
                acc3[1][ct3] = __builtin_amdgcn_mfma_f32_16x16x32_bf16(af[1].v, bw, acc3[1][ct3], 0, 0, 0);
            }
        }

        // BN2 shift + ReLU -> global
        float* ob = out + (b * 128 + mb) * 128;
#pragma unroll
        for (int ct3 = 0; ct3 < 8; ++ct3) {
            int c = ct3 * 16 + r16;
            float sh = s_sh2[c];
#pragma unroll
            for (int mt = 0; mt < 2; ++mt)
#pragma unroll
                for (int r = 0; r < 4; ++r) {
                    int row = 16 * mt + 4 * g + r;
                    ob[row * 128 + c] = fmaxf(acc3[mt][ct3][r] + sh, 0.f);
                }
        }

        // ---- load/threshold next superbatch, write vtt (acc3 dead here) ----
        if (it < 7) {
            const size_t bn = b00 + (it + 1) * 2 + bs;
            const float* vb = V + bn * 8192 + (size_t)(32 * wl + mloc) * 64 + chalf;
            f32x4 pv[8];
#pragma unroll
            for (int q = 0; q < 8; ++q) pv[q] = *(const f32x4*)(vb + 4 * q);

            const float* ab = A + bn * 16384 + (size_t)(32 * wl + r16) * 128;
            int cnt0 = 0, cnt1 = 0;
#pragma unroll
            for (int mt = 0; mt < 2; ++mt)
#pragma unroll
                for (int ks = 0; ks < 4; ++ks) {
                    const float* p = ab + mt * 2048 + ks * 32 + 8 * g;
                    f32x4 x0 = *(const f32x4*)p;
                    f32x4 x1 = *(const f32x4*)(p + 4);
                    union { unsigned short s[8]; bf16x8 v; } u;
                    u.s[0] = (x0.x >= THRESH) ? (unsigned short)0x3F80u : (unsigned short)0u;
                    u.s[1] = (x0.y >= THRESH) ? (unsigned short)0x3F80u : (unsigned short)0u;
                    u.s[2] = (x0.z >= THRESH) ? (unsigned short)0x3F80u : (unsigned short)0u;
                    u.s[3] = (x0.w >= THRESH) ? (unsigned short)0x3F80u : (unsigned short)0u;
                    u.s[4] = (x1.x >= THRESH) ? (unsigned short)0x3F80u : (unsigned short)0u;
                    u.s[5] = (x1.y >= THRESH) ? (unsigned short)0x3F80u : (unsigned short)0u;
                    u.s[6] = (x1.z >= THRESH) ? (unsigned short)0x3F80u : (unsigned short)0u;
                    u.s[7] = (x1.w >= THRESH) ? (unsigned short)0x3F80u : (unsigned short)0u;
                    afrag[mt][ks] = u.v;
                    int c = (x0.x >= THRESH) + (x0.y >= THRESH) + (x0.z >= THRESH) + (x0.w >= THRESH)
                          + (x1.x >= THRESH) + (x1.y >= THRESH) + (x1.z >= THRESH) + (x1.w >= THRESH);
                    if (mt == 0) cnt0 += c; else cnt1 += c;
                }
            cnt0 += __shfl_xor(cnt0, 16); cnt0 += __shfl_xor(cnt0, 32);
            cnt1 += __shfl_xor(cnt1, 16); cnt1 += __shfl_xor(cnt1, 32);
            dinv0 = rsqrtf((float)cnt0);
            dinv1 = rsqrtf((float)cnt1);

            float dm = (lane & 16) ? dinv1 : dinv0;
            int m = 32 * wl + mloc;
#pragma unroll
            for (int q = 0; q < 8; ++q) {
                int c = chalf + 4 * q;
                vt[(c + 0) * 136 + m] = f2bf(pv[q].x * dm);
                vt[(c + 1) * 136 + m] = f2bf(pv[q].y * dm);
                vt[(c + 2) * 136 + m] = f2bf(pv[q].z * dm);
                vt[(c + 3) * 136 + m] = f2bf(pv[q].w * dm);
            }
            __syncthreads();   // bar1: vtt(it+1) ready
        }
    }
}

extern "C" void kernel_launch(void* const* d_in, const int* in_sizes, int n_in,
                              void* d_out, int out_size, void* d_ws, size_t ws_size,
                              hipStream_t stream) {
    (void)in_sizes; (void)n_in; (void)out_size; (void)ws_size;
    const float* a   = (const float*)d_in[0];
    const float* v   = (const float*)d_in[1];
    const float* W1  = (const float*)d_in[2];
    const float* b1  = (const float*)d_in[3];
    const float* g1  = (const float*)d_in[4];
    const float* be1 = (const float*)d_in[5];
    const float* rm1 = (const float*)d_in[6];
    const float* rv1 = (const float*)d_in[7];
    const float* W2  = (const float*)d_in[8];
    const float* b2  = (const float*)d_in[9];
    const float* g2  = (const float*)d_in[10];
    const float* be2 = (const float*)d_in[11];
    const float* rm2 = (const float*)d_in[12];
    const float* rv2 = (const float*)d_in[13];

    char* ws = (char*)d_ws;
    unsigned short* W1s = (unsigned short*)ws;             // 32768 B
    unsigned short* W2s = (unsigned short*)(ws + 32768);   // 65536 B
    float* sh1 = (float*)(ws + 98304);                     // 1024 B
    float* sh2 = (float*)(ws + 99328);                     // 512 B

    gcn_prep<<<128, 256, 0, stream>>>(W1, b1, g1, be1, rm1, rv1,
                                      W2, b2, g2, be2, rm2, rv2,
                                      W1s, W2s, sh1, sh2);
    gcn_fused<<<256, 512, 0, stream>>>(a, v, W1s, W2s, sh1, sh2, (float*)d_out);
}